// Round 7
// baseline (378.355 us; speedup 1.0000x reference)
//
#include <hip/hip_runtime.h>
#include <stdint.h>

// ---------- types ----------
typedef __attribute__((ext_vector_type(8))) __bf16 bf16x8;
typedef __attribute__((ext_vector_type(4))) float f32x4;
typedef __attribute__((ext_vector_type(8))) unsigned short u16x8;
typedef __attribute__((ext_vector_type(4))) unsigned short u16x4;

#define MFMA16(a, b, c) __builtin_amdgcn_mfma_f32_16x16x32_bf16((a), (b), (c), 0, 0, 0)

__device__ __forceinline__ void glds16(const void* g, void* l) {
  __builtin_amdgcn_global_load_lds(
      (const __attribute__((address_space(1))) void*)(uintptr_t)g,
      (__attribute__((address_space(3))) void*)(uint32_t)(uintptr_t)l,
      16, 0, 0);
}

__device__ __forceinline__ unsigned short f2bf(float f) {
  union { float f; unsigned u; } v; v.f = f;
  unsigned r = v.u + 0x7FFFu + ((v.u >> 16) & 1u);
  return (unsigned short)(r >> 16);
}
__device__ __forceinline__ float bf2f(unsigned short s) {
  union { unsigned u; float f; } v; v.u = ((unsigned)s) << 16;
  return v.f;
}
__device__ __forceinline__ bf16x8 as_bf16x8(u16x8 v) {
  union { u16x8 u; bf16x8 b; } c; c.u = v; return c.b;
}

// ---------- problem constants ----------
#define B_ 32
#define N_ 512
#define C_ 1024
#define H_ 16
#define D_ 64
#define K_ C_                // 1024

// ---------- tiny kernels ----------
__global__ __launch_bounds__(256) void rope_table_kernel(float* __restrict__ sin_t,
                                                         float* __restrict__ cos_t) {
  int idx = blockIdx.x * 256 + threadIdx.x;   // 0..16383 = n*32 + i
  int n = idx >> 5, i = idx & 31;
  float div = expf(-(2.0f * (float)i) * (9.210340371976184f / 64.0f));
  float ang = (float)n * div;
  sin_t[idx] = sinf(ang);
  cos_t[idx] = cosf(ang);
}

__global__ __launch_bounds__(256) void cvt_bf16_kernel(const float* __restrict__ in,
                                                       unsigned short* __restrict__ out,
                                                       int n8) {
  int i = blockIdx.x * blockDim.x + threadIdx.x;
  if (i >= n8) return;
  const float4* p = reinterpret_cast<const float4*>(in) + (size_t)i * 2;
  float4 a = p[0], b = p[1];
  u16x8 o;
  o[0] = f2bf(a.x); o[1] = f2bf(a.y); o[2] = f2bf(a.z); o[3] = f2bf(a.w);
  o[4] = f2bf(b.x); o[5] = f2bf(b.y); o[6] = f2bf(b.z); o[7] = f2bf(b.w);
  *reinterpret_cast<u16x8*>(out + (size_t)i * 8) = o;
}

// ---------- QKV GEMM: 256x256, BK=64, quadrant phases + full-tile lookahead ----------
// (unchanged from R5/R6; 1/sqrt(D) folded into Q output)
#define STAGE_AH(bi, uu, qm)                                                      \
  do {                                                                            \
    glds16(aP0 + (size_t)(qm) * (64 * K_) + (uu) * 64, &lds[bi][(qm)*8192 + t * 8]); \
    glds16(aP1 + (size_t)(qm) * (64 * K_) + (uu) * 64,                            \
           &lds[bi][(qm)*8192 + 4096 + t * 8]);                                   \
  } while (0)
#define STAGE_BH(bi, uu, qn)                                                      \
  do {                                                                            \
    glds16(bP0 + (size_t)(qn) * (32 * K_) + (uu) * 64,                            \
           &lds[bi][16384 + (qn)*8192 + t * 8]);                                  \
    glds16(bP1 + (size_t)(qn) * (32 * K_) + (uu) * 64,                            \
           &lds[bi][16384 + (qn)*8192 + 4096 + t * 8]);                           \
  } while (0)

__global__ __launch_bounds__(512, 2) void qkv_gemm_kernel(
    const unsigned short* __restrict__ xb, const unsigned short* __restrict__ wb,
    const float* __restrict__ bias,
    unsigned short* __restrict__ Qb, unsigned short* __restrict__ Kb,
    unsigned short* __restrict__ Vtb,
    const float* __restrict__ sin_t, const float* __restrict__ cos_t) {
  __shared__ unsigned short lds[2][32768];  // 128 KB
  const int t = threadIdx.x;
  const int wv = t >> 6, l = t & 63;
  const int wr = wv >> 2, wc = wv & 3;   // 2 x 4 waves, wave tile 128x64
  const int lq = l >> 4, lr = l & 15, sx = l & 7;

  const int bid = (blockIdx.x & 7) * 96 + (blockIdx.x >> 3);
  const int mBlk = bid / 12, nBlk = bid % 12;
  const int m0 = mBlk * 256, n0 = nBlk * 256;

  const int rl = t >> 3;                       // 0..63
  const int cw = ((t & 7) ^ (rl & 7)) * 8;     // swizzled source chunk (halfwords)
  const unsigned short* aP0 = xb + (size_t)(m0 + rl) * K_ + cw;
  const unsigned short* aP1 = xb + (size_t)(m0 + 128 + rl) * K_ + cw;
  const unsigned short* bP0 = wb + (size_t)(n0 + ((rl >> 5) << 6) + (rl & 31)) * K_ + cw;
  const unsigned short* bP1 = wb + (size_t)(n0 + 128 + ((rl >> 5) << 6) + (rl & 31)) * K_ + cw;

  int aoff[2], boff[2];
#pragma unroll
  for (int s = 0; s < 2; ++s) {
    const int ch = ((s * 4 + lq) ^ sx) * 8;
    aoff[s] = (wr * 64 + lr) * 64 + ch;
    boff[s] = 16384 + (wc * 32 + lr) * 64 + ch;
  }

  f32x4 acc[8][4] = {};

  STAGE_AH(0, 0, 0); STAGE_BH(0, 0, 0); STAGE_BH(0, 0, 1); STAGE_AH(0, 0, 1);
  STAGE_AH(1, 1, 0); STAGE_BH(1, 1, 0); STAGE_BH(1, 1, 1); STAGE_AH(1, 1, 1);

  for (int u = 0; u < 16; ++u) {
    const int cur = u & 1;
    const unsigned short* Lc = &lds[cur][0];
    if (u == 15) asm volatile("s_waitcnt vmcnt(0)" ::: "memory");
    else         asm volatile("s_waitcnt vmcnt(8)" ::: "memory");
    __builtin_amdgcn_s_barrier();

    bf16x8 afr[4][2], bf0[2][2], bf1[2][2];

    // ---- ph1 (qm0,qn0): read A0 + B0
#pragma unroll
    for (int mm = 0; mm < 4; ++mm)
#pragma unroll
      for (int s = 0; s < 2; ++s)
        afr[mm][s] = *(const bf16x8*)(Lc + aoff[s] + mm * 1024);
#pragma unroll
    for (int jj = 0; jj < 2; ++jj)
#pragma unroll
      for (int s = 0; s < 2; ++s)
        bf0[jj][s] = *(const bf16x8*)(Lc + boff[s] + jj * 1024);
    asm volatile("s_waitcnt lgkmcnt(8)" ::: "memory");
    __builtin_amdgcn_s_barrier();
    asm volatile("s_waitcnt lgkmcnt(0)" ::: "memory");
    __builtin_amdgcn_s_setprio(1);
#pragma unroll
    for (int mm = 0; mm < 4; ++mm)
#pragma unroll
      for (int jj = 0; jj < 2; ++jj)
#pragma unroll
        for (int s = 0; s < 2; ++s)
          acc[mm][jj] = MFMA16(afr[mm][s], bf0[jj][s], acc[mm][jj]);
    __builtin_amdgcn_s_setprio(0);

    // ---- ph2 (qm0,qn1): read B1; stage B0+A0(u+2)
#pragma unroll
    for (int jj = 0; jj < 2; ++jj)
#pragma unroll
      for (int s = 0; s < 2; ++s)
        bf1[jj][s] = *(const bf16x8*)(Lc + boff[s] + 8192 + jj * 1024);
    if (u + 2 < 16) { STAGE_BH(cur, u + 2, 0); STAGE_AH(cur, u + 2, 0); }
    __builtin_amdgcn_s_barrier();
    asm volatile("s_waitcnt lgkmcnt(0)" ::: "memory");
    __builtin_amdgcn_s_setprio(1);
#pragma unroll
    for (int mm = 0; mm < 4; ++mm)
#pragma unroll
      for (int jj = 0; jj < 2; ++jj)
#pragma unroll
        for (int s = 0; s < 2; ++s)
          acc[mm][2 + jj] = MFMA16(afr[mm][s], bf1[jj][s], acc[mm][2 + jj]);
    __builtin_amdgcn_s_setprio(0);

    // ---- ph3 (qm1,qn1): read A1; stage B1(u+2)
#pragma unroll
    for (int mm = 0; mm < 4; ++mm)
#pragma unroll
      for (int s = 0; s < 2; ++s)
        afr[mm][s] = *(const bf16x8*)(Lc + aoff[s] + 8192 + mm * 1024);
    if (u + 2 < 16) STAGE_BH(cur, u + 2, 1);
    __builtin_amdgcn_s_barrier();
    asm volatile("s_waitcnt lgkmcnt(0)" ::: "memory");
    __builtin_amdgcn_s_setprio(1);
#pragma unroll
    for (int mm = 0; mm < 4; ++mm)
#pragma unroll
      for (int jj = 0; jj < 2; ++jj)
#pragma unroll
        for (int s = 0; s < 2; ++s)
          acc[4 + mm][2 + jj] = MFMA16(afr[mm][s], bf1[jj][s], acc[4 + mm][2 + jj]);
    __builtin_amdgcn_s_setprio(0);

    // ---- ph4 (qm1,qn0): no reads; stage A1(u+2)
    if (u + 2 < 16) STAGE_AH(cur, u + 2, 1);
    __builtin_amdgcn_s_barrier();
    __builtin_amdgcn_s_setprio(1);
#pragma unroll
    for (int mm = 0; mm < 4; ++mm)
#pragma unroll
      for (int jj = 0; jj < 2; ++jj)
#pragma unroll
        for (int s = 0; s < 2; ++s)
          acc[4 + mm][jj] = MFMA16(afr[mm][s], bf0[jj][s], acc[4 + mm][jj]);
    __builtin_amdgcn_s_setprio(0);
  }

  // ---- fused epilogue: bias + (elu+1, rope, Q*=1/8 -> Qb/Kb) or (V -> Vtb) ----
#pragma unroll
  for (int mf = 0; mf < 8; ++mf) {
#pragma unroll
    for (int j = 0; j < 4; ++j) {
      const int ncol = n0 + wc * 64 + j * 16 + lr;
      const int sel = ncol >> 10;
      const int hh = (ncol & 1023) >> 6;
      const int d = ncol & 63;
      const float bias_v = bias[ncol];
#pragma unroll
      for (int r = 0; r < 4; ++r) {
        const int m = m0 + wr * 128 + mf * 16 + lq * 4 + r;
        const int bb = m >> 9, n = m & 511;
        const float val = acc[mf][j][r] + bias_v;
        if (sel == 2) {
          Vtb[((size_t)(bb * H_ + hh) * D_ + d) * N_ + n] = f2bf(val);
        } else {
          const float e = val > 0.f ? val + 1.f : expf(val);  // elu+1
          const float partner = __shfl_xor(e, 1);
          const int ip = d >> 1;
          const float sv = sin_t[n * 32 + ip], cv = cos_t[n * 32 + ip];
          float o = (d & 1) ? (partner * sv + e * cv) : (e * cv - partner * sv);
          if (sel == 0) o *= 0.125f;  // fold 1/sqrt(D) into Q
          unsigned short* dst = (sel == 0) ? Qb : Kb;
          dst[((size_t)(bb * H_ + hh) * N_ + n) * D_ + d] = f2bf(o);
        }
      }
    }
  }
}

// ---------- attention + lepe : 2 blocks per (b,h), 2 blocks/CU ----------
// Same structure as R6; P-buffer path hardened:
//  - LDS P loads typed u16x8 (same TBAA class as the u16x4 stores), bitcast to bf16x8
//  - explicit lgkmcnt(0)+sched_barrier fences at chunk write/read boundaries
__global__ __launch_bounds__(256, 2) void attn_kernel(
    const unsigned short* __restrict__ Qb, const unsigned short* __restrict__ Kb,
    const unsigned short* __restrict__ Vtb,
    const float* __restrict__ w_lepe, const float* __restrict__ b_lepe,
    float* __restrict__ out) {
  __shared__ unsigned short Ks[512 * 64];      // 64 KB
  __shared__ unsigned short Pb[4 * 16 * 128];  // 16 KB
  const int t = threadIdx.x, wv = t >> 6, l = t & 63;
  const int lq = l >> 4, lr = l & 15;
  const int bid = blockIdx.x;
  const int bh = bid >> 1, qh = bid & 1;
  const int bb = bh >> 4, h = bh & 15;
  const size_t base = (size_t)bh * (N_ * D_);

  // stage K: 16 iters x 256 thr x 16B; dest linear, source chunk pre-swizzled
  {
    const int row = t >> 3, ch = t & 7;
#pragma unroll
    for (int c = 0; c < 16; ++c) {
      const int r = c * 32 + row;
      const int sch = ch ^ (r & 7);
      glds16(Kb + base + (size_t)r * D_ + sch * 8, Ks + c * 2048 + t * 8);
    }
  }
  asm volatile("s_waitcnt vmcnt(0)" ::: "memory");
  __builtin_amdgcn_s_barrier();

  unsigned short* Pw = Pb + wv * 2048;  // [16 q][128 k-local], 16B-slot swizzle
  const unsigned short* Vg = Vtb + base;

  for (int p = 0; p < 4; ++p) {
    const int ql = qh * 256 + wv * 64 + p * 16;
    const bf16x8 qf0 = *(const bf16x8*)(Qb + base + (size_t)(ql + lr) * D_ + lq * 8);
    const bf16x8 qf1 = *(const bf16x8*)(Qb + base + (size_t)(ql + lr) * D_ + 32 + lq * 8);

    // S^T via swapped mfma(K,Q): s[kt][r] = S[q=ql+lr][k=kt*16+lq*4+r]
    f32x4 s[32];
#pragma unroll
    for (int kt = 0; kt < 32; ++kt) {
      const int r = kt * 16 + lr;
      const int rx = r & 7;
      const unsigned short* kr = Ks + r * 64;
      const bf16x8 kf0 = *(const bf16x8*)(kr + ((lq ^ rx)) * 8);
      const bf16x8 kf1 = *(const bf16x8*)(kr + (((lq + 4)) ^ rx) * 8);
      f32x4 a = {0.f, 0.f, 0.f, 0.f};
      a = MFMA16(kf0, qf0, a);
      a = MFMA16(kf1, qf1, a);
      s[kt] = a;
    }

    // softmax for row q=ql+lr (distributed over the 4 lanes sharing lr)
    float m = -1e30f;
#pragma unroll
    for (int kt = 0; kt < 32; ++kt)
#pragma unroll
      for (int r = 0; r < 4; ++r) m = fmaxf(m, s[kt][r]);
    m = fmaxf(m, __shfl_xor(m, 16));
    m = fmaxf(m, __shfl_xor(m, 32));
    float su = 0.f;
#pragma unroll
    for (int kt = 0; kt < 32; ++kt)
#pragma unroll
      for (int r = 0; r < 4; ++r) {
        const float pv = __expf(s[kt][r] - m);   // scale pre-folded into Q
        s[kt][r] = pv;
        su += pv;
      }
    su += __shfl_xor(su, 16);
    su += __shfl_xor(su, 32);
    const float inv = 1.0f / su;

    // PV in 4 k-chunks of 128 via per-wave P buffer; V read from global (L2)
    f32x4 o[4] = {};
#pragma unroll
    for (int cc = 0; cc < 4; ++cc) {
      // WAR fence: previous chunk's P reads drained before overwrite
      asm volatile("s_waitcnt lgkmcnt(0)" ::: "memory");
      __builtin_amdgcn_sched_barrier(0);
      // write P chunk: lane q=lr owns 4 consecutive k per kl -> one b64 each
#pragma unroll
      for (int kl = 0; kl < 8; ++kl) {
        const int kt = cc * 8 + kl;
        u16x4 pk;
#pragma unroll
        for (int r = 0; r < 4; ++r) pk[r] = f2bf(s[kt][r] * inv);
        const int slot = kl * 2 + (lq >> 1);
        *(u16x4*)(Pw + lr * 128 + ((slot ^ (lr & 7)) << 3) + (lq & 1) * 4) = pk;
      }
      // RAW fence: P stores landed before cross-lane reads
      asm volatile("s_waitcnt lgkmcnt(0)" ::: "memory");
      __builtin_amdgcn_sched_barrier(0);
#pragma unroll
      for (int ks = 0; ks < 4; ++ks) {
        const u16x8 pr =
            *(const u16x8*)(Pw + lr * 128 + (((ks * 4 + lq) ^ (lr & 7)) << 3));
        const bf16x8 pf = as_bf16x8(pr);
        const int nb = cc * 128 + ks * 32 + lq * 8;
#pragma unroll
        for (int j2 = 0; j2 < 4; j2++) {
          const bf16x8 vf = *(const bf16x8*)(Vg + (size_t)(j2 * 16 + lr) * N_ + nb);
          o[j2] = MFMA16(pf, vf, o[j2]);
        }
      }
    }

    // epilogue: + lepe (conv3 over n, V from global); write fp32
    const int pb2 = ql + lq * 4;  // base n of this lane's 4 output rows
#pragma unroll
    for (int j2 = 0; j2 < 4; j2++) {
      const int d = j2 * 16 + lr;
      const int c = h * 64 + d;
      const float w0 = w_lepe[c * 3 + 0], w1 = w_lepe[c * 3 + 1], w2 = w_lepe[c * 3 + 2];
      const float bl = b_lepe[c];
      const unsigned short* rowp = Vg + (size_t)d * N_ + pb2;
      const u16x4 wm = *(const u16x4*)(rowp - 4);  // n-4..n-1 (garbage ok if pb2==0)
      const u16x4 wc_ = *(const u16x4*)(rowp);     // n..n+3
      const u16x4 wp = *(const u16x4*)(rowp + 4);  // n+4..n+7 (only [0] used)
#pragma unroll
      for (int r = 0; r < 4; r++) {
        const int n = pb2 + r;
        const float v0 = bf2f(wc_[r]);
        const float vm1 = (n > 0) ? bf2f(r == 0 ? wm[3] : wc_[(r - 1) & 3]) : 0.f;
        const float vp1 = (n < 511) ? bf2f(r == 3 ? wp[0] : wc_[(r + 1) & 3]) : 0.f;
        const float lepe = vm1 * w0 + v0 * w1 + vp1 * w2 + bl;
        out[((size_t)(bb * N_ + n)) * C_ + c] = o[j2][r] + lepe;
      }
    }
  }
}

// ---------- launcher ----------
extern "C" void kernel_launch(void* const* d_in, const int* in_sizes, int n_in,
                              void* d_out, int out_size, void* d_ws, size_t ws_size,
                              hipStream_t stream) {
  (void)in_sizes; (void)n_in; (void)out_size; (void)ws_size;
  const float* x = (const float*)d_in[0];
  const float* w_qkv = (const float*)d_in[1];
  const float* b_qkv = (const float*)d_in[2];
  const float* w_lepe = (const float*)d_in[3];
  const float* b_lepe = (const float*)d_in[4];
  float* out = (float*)d_out;

  unsigned short* ws = (unsigned short*)d_ws;
  unsigned short* xb = ws;                          // 16777216 el
  unsigned short* wb = xb + 16777216;               // 3145728 el
  unsigned short* Qb = wb + 3145728;                // 16777216 el
  unsigned short* Kb = Qb + 16777216;               // 16777216 el
  unsigned short* Vtb = Kb + 16777216;              // 16777216 el
  float* sin_t = (float*)(Vtb + 16777216);          // 16384 f32
  float* cos_t = sin_t + 16384;                     // 16384 f32

  rope_table_kernel<<<64, 256, 0, stream>>>(sin_t, cos_t);
  cvt_bf16_kernel<<<(16777216 / 8 + 255) / 256, 256, 0, stream>>>(x, xb, 16777216 / 8);
  cvt_bf16_kernel<<<(3145728 / 8 + 255) / 256, 256, 0, stream>>>(w_qkv, wb, 3145728 / 8);
  qkv_gemm_kernel<<<768, 512, 0, stream>>>(xb, wb, b_qkv, Qb, Kb, Vtb, sin_t, cos_t);
  attn_kernel<<<1024, 256, 0, stream>>>(Qb, Kb, Vtb, w_lepe, b_lepe, out);
}

// Round 8
// 276.179 us; speedup vs baseline: 1.3700x; 1.3700x over previous
//
#include <hip/hip_runtime.h>
#include <stdint.h>

// ---------- types ----------
typedef __attribute__((ext_vector_type(8))) __bf16 bf16x8;
typedef __attribute__((ext_vector_type(4))) float f32x4;
typedef __attribute__((ext_vector_type(8))) unsigned short u16x8;
typedef __attribute__((ext_vector_type(4))) unsigned short u16x4;

#define MFMA16(a, b, c) __builtin_amdgcn_mfma_f32_16x16x32_bf16((a), (b), (c), 0, 0, 0)

__device__ __forceinline__ void glds16(const void* g, void* l) {
  __builtin_amdgcn_global_load_lds(
      (const __attribute__((address_space(1))) void*)(uintptr_t)g,
      (__attribute__((address_space(3))) void*)(uint32_t)(uintptr_t)l,
      16, 0, 0);
}

__device__ __forceinline__ unsigned short f2bf(float f) {
  union { float f; unsigned u; } v; v.f = f;
  unsigned r = v.u + 0x7FFFu + ((v.u >> 16) & 1u);
  return (unsigned short)(r >> 16);
}
__device__ __forceinline__ float bf2f(unsigned short s) {
  union { unsigned u; float f; } v; v.u = ((unsigned)s) << 16;
  return v.f;
}
__device__ __forceinline__ bf16x8 as_bf16x8(u16x8 v) {
  union { u16x8 u; bf16x8 b; } c; c.u = v; return c.b;
}

// ---------- problem constants ----------
#define B_ 32
#define N_ 512
#define C_ 1024
#define H_ 16
#define D_ 64
#define K_ C_                // 1024

// ---------- tiny kernels ----------
__global__ __launch_bounds__(256) void rope_table_kernel(float* __restrict__ sin_t,
                                                         float* __restrict__ cos_t) {
  int idx = blockIdx.x * 256 + threadIdx.x;   // 0..16383 = n*32 + i
  int n = idx >> 5, i = idx & 31;
  float div = expf(-(2.0f * (float)i) * (9.210340371976184f / 64.0f));
  float ang = (float)n * div;
  sin_t[idx] = sinf(ang);
  cos_t[idx] = cosf(ang);
}

__global__ __launch_bounds__(256) void cvt_bf16_kernel(const float* __restrict__ in,
                                                       unsigned short* __restrict__ out,
                                                       int n8) {
  int i = blockIdx.x * blockDim.x + threadIdx.x;
  if (i >= n8) return;
  const float4* p = reinterpret_cast<const float4*>(in) + (size_t)i * 2;
  float4 a = p[0], b = p[1];
  u16x8 o;
  o[0] = f2bf(a.x); o[1] = f2bf(a.y); o[2] = f2bf(a.z); o[3] = f2bf(a.w);
  o[4] = f2bf(b.x); o[5] = f2bf(b.y); o[6] = f2bf(b.z); o[7] = f2bf(b.w);
  *reinterpret_cast<u16x8*>(out + (size_t)i * 8) = o;
}

// ---------- QKV GEMM: 256x256, BK=64, quadrant phases + full-tile lookahead ----------
// (unchanged from R7, passing; 1/sqrt(D) folded into Q output)
#define STAGE_AH(bi, uu, qm)                                                      \
  do {                                                                            \
    glds16(aP0 + (size_t)(qm) * (64 * K_) + (uu) * 64, &lds[bi][(qm)*8192 + t * 8]); \
    glds16(aP1 + (size_t)(qm) * (64 * K_) + (uu) * 64,                            \
           &lds[bi][(qm)*8192 + 4096 + t * 8]);                                   \
  } while (0)
#define STAGE_BH(bi, uu, qn)                                                      \
  do {                                                                            \
    glds16(bP0 + (size_t)(qn) * (32 * K_) + (uu) * 64,                            \
           &lds[bi][16384 + (qn)*8192 + t * 8]);                                  \
    glds16(bP1 + (size_t)(qn) * (32 * K_) + (uu) * 64,                            \
           &lds[bi][16384 + (qn)*8192 + 4096 + t * 8]);                           \
  } while (0)

__global__ __launch_bounds__(512, 2) void qkv_gemm_kernel(
    const unsigned short* __restrict__ xb, const unsigned short* __restrict__ wb,
    const float* __restrict__ bias,
    unsigned short* __restrict__ Qb, unsigned short* __restrict__ Kb,
    unsigned short* __restrict__ Vtb,
    const float* __restrict__ sin_t, const float* __restrict__ cos_t) {
  __shared__ unsigned short lds[2][32768];  // 128 KB
  const int t = threadIdx.x;
  const int wv = t >> 6, l = t & 63;
  const int wr = wv >> 2, wc = wv & 3;   // 2 x 4 waves, wave tile 128x64
  const int lq = l >> 4, lr = l & 15, sx = l & 7;

  const int bid = (blockIdx.x & 7) * 96 + (blockIdx.x >> 3);
  const int mBlk = bid / 12, nBlk = bid % 12;
  const int m0 = mBlk * 256, n0 = nBlk * 256;

  const int rl = t >> 3;                       // 0..63
  const int cw = ((t & 7) ^ (rl & 7)) * 8;     // swizzled source chunk (halfwords)
  const unsigned short* aP0 = xb + (size_t)(m0 + rl) * K_ + cw;
  const unsigned short* aP1 = xb + (size_t)(m0 + 128 + rl) * K_ + cw;
  const unsigned short* bP0 = wb + (size_t)(n0 + ((rl >> 5) << 6) + (rl & 31)) * K_ + cw;
  const unsigned short* bP1 = wb + (size_t)(n0 + 128 + ((rl >> 5) << 6) + (rl & 31)) * K_ + cw;

  int aoff[2], boff[2];
#pragma unroll
  for (int s = 0; s < 2; ++s) {
    const int ch = ((s * 4 + lq) ^ sx) * 8;
    aoff[s] = (wr * 64 + lr) * 64 + ch;
    boff[s] = 16384 + (wc * 32 + lr) * 64 + ch;
  }

  f32x4 acc[8][4] = {};

  STAGE_AH(0, 0, 0); STAGE_BH(0, 0, 0); STAGE_BH(0, 0, 1); STAGE_AH(0, 0, 1);
  STAGE_AH(1, 1, 0); STAGE_BH(1, 1, 0); STAGE_BH(1, 1, 1); STAGE_AH(1, 1, 1);

  for (int u = 0; u < 16; ++u) {
    const int cur = u & 1;
    const unsigned short* Lc = &lds[cur][0];
    if (u == 15) asm volatile("s_waitcnt vmcnt(0)" ::: "memory");
    else         asm volatile("s_waitcnt vmcnt(8)" ::: "memory");
    __builtin_amdgcn_s_barrier();

    bf16x8 afr[4][2], bf0[2][2], bf1[2][2];

    // ---- ph1 (qm0,qn0): read A0 + B0
#pragma unroll
    for (int mm = 0; mm < 4; ++mm)
#pragma unroll
      for (int s = 0; s < 2; ++s)
        afr[mm][s] = *(const bf16x8*)(Lc + aoff[s] + mm * 1024);
#pragma unroll
    for (int jj = 0; jj < 2; ++jj)
#pragma unroll
      for (int s = 0; s < 2; ++s)
        bf0[jj][s] = *(const bf16x8*)(Lc + boff[s] + jj * 1024);
    asm volatile("s_waitcnt lgkmcnt(8)" ::: "memory");
    __builtin_amdgcn_s_barrier();
    asm volatile("s_waitcnt lgkmcnt(0)" ::: "memory");
    __builtin_amdgcn_s_setprio(1);
#pragma unroll
    for (int mm = 0; mm < 4; ++mm)
#pragma unroll
      for (int jj = 0; jj < 2; ++jj)
#pragma unroll
        for (int s = 0; s < 2; ++s)
          acc[mm][jj] = MFMA16(afr[mm][s], bf0[jj][s], acc[mm][jj]);
    __builtin_amdgcn_s_setprio(0);

    // ---- ph2 (qm0,qn1): read B1; stage B0+A0(u+2)
#pragma unroll
    for (int jj = 0; jj < 2; ++jj)
#pragma unroll
      for (int s = 0; s < 2; ++s)
        bf1[jj][s] = *(const bf16x8*)(Lc + boff[s] + 8192 + jj * 1024);
    if (u + 2 < 16) { STAGE_BH(cur, u + 2, 0); STAGE_AH(cur, u + 2, 0); }
    __builtin_amdgcn_s_barrier();
    asm volatile("s_waitcnt lgkmcnt(0)" ::: "memory");
    __builtin_amdgcn_s_setprio(1);
#pragma unroll
    for (int mm = 0; mm < 4; ++mm)
#pragma unroll
      for (int jj = 0; jj < 2; ++jj)
#pragma unroll
        for (int s = 0; s < 2; ++s)
          acc[mm][2 + jj] = MFMA16(afr[mm][s], bf1[jj][s], acc[mm][2 + jj]);
    __builtin_amdgcn_s_setprio(0);

    // ---- ph3 (qm1,qn1): read A1; stage B1(u+2)
#pragma unroll
    for (int mm = 0; mm < 4; ++mm)
#pragma unroll
      for (int s = 0; s < 2; ++s)
        afr[mm][s] = *(const bf16x8*)(Lc + aoff[s] + 8192 + mm * 1024);
    if (u + 2 < 16) STAGE_BH(cur, u + 2, 1);
    __builtin_amdgcn_s_barrier();
    asm volatile("s_waitcnt lgkmcnt(0)" ::: "memory");
    __builtin_amdgcn_s_setprio(1);
#pragma unroll
    for (int mm = 0; mm < 4; ++mm)
#pragma unroll
      for (int jj = 0; jj < 2; ++jj)
#pragma unroll
        for (int s = 0; s < 2; ++s)
          acc[4 + mm][2 + jj] = MFMA16(afr[mm][s], bf1[jj][s], acc[4 + mm][2 + jj]);
    __builtin_amdgcn_s_setprio(0);

    // ---- ph4 (qm1,qn0): no reads; stage A1(u+2)
    if (u + 2 < 16) STAGE_AH(cur, u + 2, 1);
    __builtin_amdgcn_s_barrier();
    __builtin_amdgcn_s_setprio(1);
#pragma unroll
    for (int mm = 0; mm < 4; ++mm)
#pragma unroll
      for (int jj = 0; jj < 2; ++jj)
#pragma unroll
        for (int s = 0; s < 2; ++s)
          acc[4 + mm][jj] = MFMA16(afr[mm][s], bf0[jj][s], acc[4 + mm][jj]);
    __builtin_amdgcn_s_setprio(0);
  }

  // ---- fused epilogue: bias + (elu+1, rope, Q*=1/8 -> Qb/Kb) or (V -> Vtb) ----
#pragma unroll
  for (int mf = 0; mf < 8; ++mf) {
#pragma unroll
    for (int j = 0; j < 4; ++j) {
      const int ncol = n0 + wc * 64 + j * 16 + lr;
      const int sel = ncol >> 10;
      const int hh = (ncol & 1023) >> 6;
      const int d = ncol & 63;
      const float bias_v = bias[ncol];
#pragma unroll
      for (int r = 0; r < 4; ++r) {
        const int m = m0 + wr * 128 + mf * 16 + lq * 4 + r;
        const int bb = m >> 9, n = m & 511;
        const float val = acc[mf][j][r] + bias_v;
        if (sel == 2) {
          Vtb[((size_t)(bb * H_ + hh) * D_ + d) * N_ + n] = f2bf(val);
        } else {
          const float e = val > 0.f ? val + 1.f : expf(val);  // elu+1
          const float partner = __shfl_xor(e, 1);
          const int ip = d >> 1;
          const float sv = sin_t[n * 32 + ip], cv = cos_t[n * 32 + ip];
          float o = (d & 1) ? (partner * sv + e * cv) : (e * cv - partner * sv);
          if (sel == 0) o *= 0.125f;  // fold 1/sqrt(D) into Q
          unsigned short* dst = (sel == 0) ? Qb : Kb;
          dst[((size_t)(bb * H_ + hh) * N_ + n) * D_ + d] = f2bf(o);
        }
      }
    }
  }
}

// ---------- attention + lepe : one block per (b,h) (R5 shell) ----------
// block 512 = 8 waves; wave owns 64 q rows (4 p-iters of 16).
// LDS: Ks [512][64] swz 64KB + Vs [64][512] swz 64KB + P 8x4KB = 160KB.
// Swapped QK^T (mfma(K,Q)): lane holds S[q=lr][k=kt*16+lq*4+r] -> scalar softmax,
// 2-shfl reduce, b64 P-writes; P path type-consistent (u16) + fenced (R7).
__global__ __launch_bounds__(512, 2) void attn_kernel(
    const unsigned short* __restrict__ Qb, const unsigned short* __restrict__ Kb,
    const unsigned short* __restrict__ Vtb,
    const float* __restrict__ w_lepe, const float* __restrict__ b_lepe,
    float* __restrict__ out) {
  __shared__ unsigned short Ks[512 * 64];      // 64 KB
  __shared__ unsigned short Vs[64 * 512];      // 64 KB
  __shared__ unsigned short Pb[8 * 16 * 128];  // 32 KB
  const int t = threadIdx.x, wv = t >> 6, l = t & 63;
  const int lq = l >> 4, lr = l & 15;
  const int bh = blockIdx.x;           // 0..511
  const int bb = bh >> 4, h = bh & 15;
  const size_t base = (size_t)bh * (N_ * D_);

  // stage K: 8 iters, 512 thr x 16B; dest linear, source chunk pre-swizzled
  {
    const int row8 = t >> 3, ch = t & 7;
#pragma unroll
    for (int c = 0; c < 8; ++c) {
      const int r = c * 64 + row8;
      const int sch = ch ^ (r & 7);
      glds16(Kb + base + (size_t)r * D_ + sch * 8, Ks + c * 4096 + t * 8);
    }
  }
  // stage Vt: 8 iters; wave w stages row d = c*8+w
  {
    const int ch = t & 63;
#pragma unroll
    for (int c = 0; c < 8; ++c) {
      const int d = c * 8 + wv;
      const int sch = ch ^ (d & 7);
      glds16(Vtb + base + (size_t)d * N_ + sch * 8, Vs + c * 4096 + t * 8);
    }
  }

  // wait K only (oldest 8 of 16 outstanding per lane), keep V in flight
  asm volatile("s_waitcnt vmcnt(8)" ::: "memory");
  __builtin_amdgcn_s_barrier();

  unsigned short* Pw = Pb + wv * 2048;  // [16 q][128 k-local], 16B-slot swizzle

  for (int p = 0; p < 4; ++p) {
    const int ql = wv * 64 + p * 16;
    const bf16x8 qf0 = *(const bf16x8*)(Qb + base + (size_t)(ql + lr) * D_ + lq * 8);
    const bf16x8 qf1 = *(const bf16x8*)(Qb + base + (size_t)(ql + lr) * D_ + 32 + lq * 8);

    // S^T via swapped mfma(K,Q): s[kt][r] = S[q=ql+lr][k=kt*16+lq*4+r]
    f32x4 s[32];
#pragma unroll
    for (int kt = 0; kt < 32; ++kt) {
      const int r = kt * 16 + lr;
      const int rx = r & 7;
      const unsigned short* kr = Ks + r * 64;
      const bf16x8 kf0 = *(const bf16x8*)(kr + (lq ^ rx) * 8);
      const bf16x8 kf1 = *(const bf16x8*)(kr + ((lq + 4) ^ rx) * 8);
      f32x4 a = {0.f, 0.f, 0.f, 0.f};
      a = MFMA16(kf0, qf0, a);
      a = MFMA16(kf1, qf1, a);
      s[kt] = a;
    }

    // softmax for row q=ql+lr (distributed over the 4 lanes sharing lr)
    float m = -1e30f;
#pragma unroll
    for (int kt = 0; kt < 32; ++kt)
#pragma unroll
      for (int r = 0; r < 4; ++r) m = fmaxf(m, s[kt][r]);
    m = fmaxf(m, __shfl_xor(m, 16));
    m = fmaxf(m, __shfl_xor(m, 32));
    float su = 0.f;
#pragma unroll
    for (int kt = 0; kt < 32; ++kt)
#pragma unroll
      for (int r = 0; r < 4; ++r) {
        const float pv = __expf(s[kt][r] - m);   // scale pre-folded into Q
        s[kt][r] = pv;
        su += pv;
      }
    su += __shfl_xor(su, 16);
    su += __shfl_xor(su, 32);
    const float inv = 1.0f / su;

    if (p == 0) __syncthreads();  // V staged (drains vmcnt); all waves reach once

    // PV in 4 k-chunks of 128 via per-wave P buffer; V from LDS
    f32x4 o[4] = {};
#pragma unroll
    for (int cc = 0; cc < 4; ++cc) {
      // WAR fence: previous chunk's P reads drained before overwrite
      asm volatile("s_waitcnt lgkmcnt(0)" ::: "memory");
      __builtin_amdgcn_sched_barrier(0);
      // write P chunk: lane q=lr owns 4 consecutive k per kl -> one b64 each
#pragma unroll
      for (int kl = 0; kl < 8; ++kl) {
        const int kt = cc * 8 + kl;
        u16x4 pk;
#pragma unroll
        for (int r = 0; r < 4; ++r) pk[r] = f2bf(s[kt][r] * inv);
        const int slot = kl * 2 + (lq >> 1);
        *(u16x4*)(Pw + lr * 128 + ((slot ^ (lr & 7)) << 3) + (lq & 1) * 4) = pk;
      }
      // RAW fence: P stores landed before cross-lane reads
      asm volatile("s_waitcnt lgkmcnt(0)" ::: "memory");
      __builtin_amdgcn_sched_barrier(0);
#pragma unroll
      for (int ks = 0; ks < 4; ++ks) {
        const u16x8 pr =
            *(const u16x8*)(Pw + lr * 128 + (((ks * 4 + lq) ^ (lr & 7)) << 3));
        const bf16x8 pf = as_bf16x8(pr);
        const int ci = cc * 16 + ks * 4 + lq;
#pragma unroll
        for (int j2 = 0; j2 < 4; j2++) {
          const int dr = j2 * 16 + lr;
          const bf16x8 vf = *(const bf16x8*)(Vs + dr * 512 + ((ci ^ (dr & 7)) << 3));
          o[j2] = MFMA16(pf, vf, o[j2]);
        }
      }
    }

    // epilogue: + lepe (depthwise conv3 over n from resident Vs); write fp32
#pragma unroll
    for (int j2 = 0; j2 < 4; j2++) {
      const int d = j2 * 16 + lr;
      const int c = h * 64 + d;
      const float w0 = w_lepe[c * 3 + 0], w1 = w_lepe[c * 3 + 1], w2 = w_lepe[c * 3 + 2];
      const float bl = b_lepe[c];
      const int dx = d & 7;
#pragma unroll
      for (int r = 0; r < 4; r++) {
        const int n = ql + lq * 4 + r;
        float vm1 = 0.f, vp1 = 0.f;
        if (n > 0) {
          const int nn = n - 1;
          vm1 = bf2f(Vs[d * 512 + (((nn >> 3) ^ dx) << 3) + (nn & 7)]);
        }
        const float v0 = bf2f(Vs[d * 512 + (((n >> 3) ^ dx) << 3) + (n & 7)]);
        if (n < 511) {
          const int nn = n + 1;
          vp1 = bf2f(Vs[d * 512 + (((nn >> 3) ^ dx) << 3) + (nn & 7)]);
        }
        const float lepe = vm1 * w0 + v0 * w1 + vp1 * w2 + bl;
        out[((size_t)(bb * N_ + n)) * C_ + c] = o[j2][r] + lepe;
      }
    }
  }
}

// ---------- launcher ----------
extern "C" void kernel_launch(void* const* d_in, const int* in_sizes, int n_in,
                              void* d_out, int out_size, void* d_ws, size_t ws_size,
                              hipStream_t stream) {
  (void)in_sizes; (void)n_in; (void)out_size; (void)ws_size;
  const float* x = (const float*)d_in[0];
  const float* w_qkv = (const float*)d_in[1];
  const float* b_qkv = (const float*)d_in[2];
  const float* w_lepe = (const float*)d_in[3];
  const float* b_lepe = (const float*)d_in[4];
  float* out = (float*)d_out;

  unsigned short* ws = (unsigned short*)d_ws;
  unsigned short* xb = ws;                          // 16777216 el
  unsigned short* wb = xb + 16777216;               // 3145728 el
  unsigned short* Qb = wb + 3145728;                // 16777216 el
  unsigned short* Kb = Qb + 16777216;               // 16777216 el
  unsigned short* Vtb = Kb + 16777216;              // 16777216 el
  float* sin_t = (float*)(Vtb + 16777216);          // 16384 f32
  float* cos_t = sin_t + 16384;                     // 16384 f32

  rope_table_kernel<<<64, 256, 0, stream>>>(sin_t, cos_t);
  cvt_bf16_kernel<<<(16777216 / 8 + 255) / 256, 256, 0, stream>>>(x, xb, 16777216 / 8);
  cvt_bf16_kernel<<<(3145728 / 8 + 255) / 256, 256, 0, stream>>>(w_qkv, wb, 3145728 / 8);
  qkv_gemm_kernel<<<768, 512, 0, stream>>>(xb, wb, b_qkv, Qb, Kb, Vtb, sin_t, cos_t);
  attn_kernel<<<512, 512, 0, stream>>>(Qb, Kb, Vtb, w_lepe, b_lepe, out);
}